// Round 7
// baseline (683.186 us; speedup 1.0000x reference)
//
#include <hip/hip_runtime.h>
#include <stdint.h>

static constexpr int kN   = 50000;   // nodes
static constexpr int kCap = 64;      // adjacency capacity per node (Poisson(12) tail @64 ~ 1e-25)
static constexpr int kRowB = 192;    // adjacency row bytes: [cnt:int][64 x u16 slots][pad] (3 lines)
static constexpr int kW2TBlocks = 16;    // 16*256 = 4096 = W2T dwords
static constexpr int kGemm1Blocks = 1564;  // 782 rb-groups x 2 cg

typedef __attribute__((ext_vector_type(8))) _Float16 f16x8;  // MFMA A/B fragment
typedef __attribute__((ext_vector_type(2))) _Float16 f16x2;  // packed pair -> v_pk_add_f16
typedef __attribute__((ext_vector_type(4))) float f32x4;     // MFMA 16x16 accumulator

// ---------------- threefry2x32-20 (verified vs Random123 KAT) ----------------
__device__ __forceinline__ uint32_t rotl32(uint32_t v, uint32_t r) {
  return (v << r) | (v >> (32u - r));
}

__device__ __forceinline__ uint2 threefry2x32(uint32_t k0, uint32_t k1,
                                              uint32_t x0, uint32_t x1) {
  const uint32_t k2 = k0 ^ k1 ^ 0x1BD11BDAu;
  x0 += k0; x1 += k1;
#define TFR(r) { x0 += x1; x1 = rotl32(x1, r); x1 ^= x0; }
  TFR(13u) TFR(15u) TFR(26u) TFR(6u)
  x0 += k1; x1 += k2 + 1u;
  TFR(17u) TFR(29u) TFR(16u) TFR(24u)
  x0 += k2; x1 += k0 + 2u;
  TFR(13u) TFR(15u) TFR(26u) TFR(6u)
  x0 += k0; x1 += k1 + 3u;
  TFR(17u) TFR(29u) TFR(16u) TFR(24u)
  x0 += k1; x1 += k2 + 4u;
  TFR(13u) TFR(15u) TFR(26u) TFR(6u)
  x0 += k2; x1 += k0 + 5u;
#undef TFR
  return make_uint2(x0, x1);
}

__device__ __forceinline__ bool drop_elem(uint32_t j) {
  const uint2 r = threefry2x32(0u, 42u, 0u, j);
  return ((r.x ^ r.y) >> 31) != 0u;
}

// ---------------- f16 pack/unpack ----------------
union PairU { f16x2 h; uint32_t u; };
__device__ __forceinline__ uint32_t pack_f16x2(float lo, float hi) {
  PairU p; p.h[0] = (_Float16)lo; p.h[1] = (_Float16)hi; return p.u;
}
__device__ __forceinline__ float f16_lo(f16x2 v) { return (float)v[0]; }
__device__ __forceinline__ float f16_hi(f16x2 v) { return (float)v[1]; }

__device__ __forceinline__ void pk_acc(uint32_t& acc, uint32_t v) {
  PairU a, b; a.u = acc; b.u = v; a.h += b.h; acc = a.u;
}

union FragU { uint4 q; f16x8 f; };

// ---------------- software grid barrier (generation counter in d_ws, memset-zeroed) ----
// Safe because grid <= co-resident capacity (sized via occupancy query on host).
__device__ __forceinline__ void grid_barrier(int* bar) {
  __syncthreads();
  if (threadIdx.x == 0) {
    __threadfence();
    int* cnt = bar;
    int* gen = bar + 1;
    const int g = __hip_atomic_load(gen, __ATOMIC_RELAXED, __HIP_MEMORY_SCOPE_AGENT);
    const int a = __hip_atomic_fetch_add(cnt, 1, __ATOMIC_ACQ_REL, __HIP_MEMORY_SCOPE_AGENT);
    if (a + 1 == (int)gridDim.x) {
      __hip_atomic_store(cnt, 0, __ATOMIC_RELAXED, __HIP_MEMORY_SCOPE_AGENT);
      __hip_atomic_store(gen, g + 1, __ATOMIC_RELEASE, __HIP_MEMORY_SCOPE_AGENT);
    } else {
      while (__hip_atomic_load(gen, __ATOMIC_ACQUIRE, __HIP_MEMORY_SCOPE_AGENT) == g) {
        __builtin_amdgcn_s_sleep(8);
      }
    }
    __threadfence();
  }
  __syncthreads();
}

// ================== FUSED single-kernel pipeline ==================
// P1: adj-build | W2T-pack | gemm1 (grid-stride over virtual blocks)
// P2: agg1 + gemm2 (grid-stride, 6250 tiles)
// P3: agg_out (grid-stride, 6250 tiles)
// All phase bodies are byte-identical to the verified r6 kernels.
__global__ __launch_bounds__(256, 8) void fused_gin(
    const float* __restrict__ x, const float* __restrict__ W1,
    const float* __restrict__ W2, uint32_t* __restrict__ W2T,
    const int* __restrict__ src, const int* __restrict__ dst,
    uint8_t* __restrict__ adjr, int E, int adjBlocks,
    uint32_t* __restrict__ z1h, const float* __restrict__ b1,
    const uint32_t* __restrict__ zpad, uint32_t* __restrict__ z2h,
    const float* __restrict__ b2, float* __restrict__ out,
    int* __restrict__ bar) {
  __shared__ uint32_t LDS[64 * 68 + 8 * 68];  // 19.6 KB union (P1 uses first 16 KB)

  const int tid = threadIdx.x;
  const int bid = blockIdx.x;
  const int nb  = gridDim.x;
  const int lane = tid & 63;
  const int wid  = tid >> 6;

  // ---------------- P1 ----------------
  const int nVB1 = adjBlocks + kW2TBlocks + kGemm1Blocks;
  for (int vb = bid; vb < nVB1; vb += nb) {
    if (vb < adjBlocks) {
      const int base = vb * 1024 + tid;
      int d[4], s[4];
      bool ok[4];
#pragma unroll
      for (int j = 0; j < 4; ++j) {
        const int e = base + j * 256;
        ok[j] = (e < E);
        d[j] = ok[j] ? dst[e] : 0;
        s[j] = ok[j] ? src[e] : 0;
      }
      int slot[4];
#pragma unroll
      for (int j = 0; j < 4; ++j)
        slot[j] = ok[j] ? atomicAdd((int*)(adjr + (size_t)d[j] * kRowB), 1) : kCap;
#pragma unroll
      for (int j = 0; j < 4; ++j)
        if (ok[j] && slot[j] < kCap)
          *(uint16_t*)(adjr + (size_t)d[j] * kRowB + 4 + 2 * slot[j]) = (uint16_t)s[j];
    } else if (vb < adjBlocks + kW2TBlocks) {
      const int w = (vb - adjBlocks) * 256 + tid;  // < 4096
      const int n = w >> 6, i = w & 63;
      W2T[w] = pack_f16x2(W2[(size_t)(2 * i) * 64 + n], W2[(size_t)(2 * i + 1) * 64 + n]);
    } else {
      const int gb = vb - adjBlocks - kW2TBlocks;  // 0..1563
      const int cg = gb & 1;
      // Stage this cg's half of W1, fragment-major (conflict-free B-fragment reads).
      for (int v = tid; v < 64 * 64; v += 256) {
        const int i  = v >> 6;
        const int nl = v & 63;
        const int kb = i >> 4, r = i & 15;
        const int quad_s = r >> 2, c = r & 3;
        const int ct = nl >> 4, mrow_s = nl & 15;
        const int n = cg * 64 + nl;
        LDS[((ct * 4 + kb) * 4 + quad_s) * 64 + mrow_s * 4 + c] =
            pack_f16x2(W1[(size_t)(2 * i) * 128 + n], W1[(size_t)(2 * i + 1) * 128 + n]);
      }
      __syncthreads();
      const int rb = (gb >> 1) * 4 + wid;  // -> rb 0..3127
      if (rb < 3125) {
        const int n0   = rb * 16;
        const int quad = lane >> 4;
        const int mrow = lane & 15;
        const float* xp = x + (size_t)(n0 + mrow) * 128 + quad * 8;
        f32x4 acc[4] = {{0.f,0.f,0.f,0.f},{0.f,0.f,0.f,0.f},{0.f,0.f,0.f,0.f},{0.f,0.f,0.f,0.f}};
#pragma unroll
        for (int kb = 0; kb < 4; ++kb) {
          const float4 lo = *reinterpret_cast<const float4*>(xp + kb * 32);
          const float4 hi = *reinterpret_cast<const float4*>(xp + kb * 32 + 4);
          FragU a;
          a.q = make_uint4(pack_f16x2(lo.x, lo.y), pack_f16x2(lo.z, lo.w),
                           pack_f16x2(hi.x, hi.y), pack_f16x2(hi.z, hi.w));
#pragma unroll
          for (int ct = 0; ct < 4; ++ct) {
            FragU b;
            b.q = *reinterpret_cast<const uint4*>(&LDS[((ct * 4 + kb) * 4 + quad) * 64 + mrow * 4]);
            acc[ct] = __builtin_amdgcn_mfma_f32_16x16x32_f16(a.f, b.f, acc[ct], 0, 0, 0);
          }
        }
#pragma unroll
        for (int ct = 0; ct < 4; ++ct) {
#pragma unroll
          for (int r = 0; r < 4; ++r) {
            const float v = acc[ct][r];
            const float vOdd = __shfl(v, lane | 1);
            if ((lane & 1) == 0) {
              const int row = n0 + quad * 4 + r;
              z1h[(size_t)row * 64 + cg * 32 + ct * 8 + (mrow >> 1)] = pack_f16x2(v, vOdd);
            }
          }
        }
      }
      __syncthreads();  // WAR: protect LDS before next-iteration restage
    }
  }

  grid_barrier(bar);

  // ---------------- P2: agg1 + gemm2 ----------------
  uint32_t* WT = LDS;
  uint32_t* HT = LDS + 64 * 68;
  for (int v = tid; v < 64 * 64; v += 256)
    WT[(v >> 6) * 68 + (v & 63)] = W2T[v];

  const uint4* zq = reinterpret_cast<const uint4*>(zpad);
  const int g  = lane >> 4;
  const int fl = lane & 15;

  for (int vb = bid; vb < 6250; vb += nb) {
    __syncthreads();  // covers WT staging (1st iter) + HT WAR (later iters)
    const int n0 = vb * 8;
    const int nA = n0 + 2 * wid, nB = nA + 1;

    const uint8_t* rowA = adjr + (size_t)nA * kRowB;
    const uint8_t* rowB = adjr + (size_t)nB * kRowB;
    const int vaA = *(const uint16_t*)(rowA + 4 + 2 * lane);
    const int vaB = *(const uint16_t*)(rowB + 4 + 2 * lane);
    int dA = __builtin_amdgcn_readfirstlane(*(const int*)rowA); if (dA > kCap) dA = kCap;
    int dB = __builtin_amdgcn_readfirstlane(*(const int*)rowB); if (dB > kCap) dB = kCap;
    const int dm = (dA > dB) ? dA : dB;

    uint32_t aA[4], aB[4];
    {
      const uint4* pa = (g == 0) ? reinterpret_cast<const uint4*>(z1h + (size_t)nA * 64) : zq;
      const uint4* pb = (g == 0) ? reinterpret_cast<const uint4*>(z1h + (size_t)nB * 64) : zq;
      const uint4 va = pa[fl];
      const uint4 vb2 = pb[fl];
      aA[0] = va.x; aA[1] = va.y; aA[2] = va.z; aA[3] = va.w;
      aB[0] = vb2.x; aB[1] = vb2.y; aB[2] = vb2.z; aB[3] = vb2.w;
    }

    for (int e = 0; e < dm; e += 16) {
      uint4 lA[4], lB[4];
#pragma unroll
      for (int j = 0; j < 4; ++j) {
        const int sl = e + j * 4 + g;
        const int ia = __shfl(vaA, sl);
        const uint4* pa = (sl < dA) ? reinterpret_cast<const uint4*>(z1h + (size_t)ia * 64) : zq;
        lA[j] = pa[fl];
      }
#pragma unroll
      for (int j = 0; j < 4; ++j) {
        const int sl = e + j * 4 + g;
        const int ib = __shfl(vaB, sl);
        const uint4* pb = (sl < dB) ? reinterpret_cast<const uint4*>(z1h + (size_t)ib * 64) : zq;
        lB[j] = pb[fl];
      }
#pragma unroll
      for (int j = 0; j < 4; ++j) {
        pk_acc(aA[0], lA[j].x); pk_acc(aA[1], lA[j].y);
        pk_acc(aA[2], lA[j].z); pk_acc(aA[3], lA[j].w);
        pk_acc(aB[0], lB[j].x); pk_acc(aB[1], lB[j].y);
        pk_acc(aB[2], lB[j].z); pk_acc(aB[3], lB[j].w);
      }
    }

#pragma unroll
    for (int c = 0; c < 4; ++c) {
      uint32_t t;
      t = (uint32_t)__shfl_xor((int)aA[c], 16); pk_acc(aA[c], t);
      t = (uint32_t)__shfl_xor((int)aA[c], 32); pk_acc(aA[c], t);
      t = (uint32_t)__shfl_xor((int)aB[c], 16); pk_acc(aB[c], t);
      t = (uint32_t)__shfl_xor((int)aB[c], 32); pk_acc(aB[c], t);
    }

    const int d = 4 * fl + g;
    const uint32_t mA = (g & 2) ? ((g & 1) ? aA[3] : aA[2]) : ((g & 1) ? aA[1] : aA[0]);
    const uint32_t mB = (g & 2) ? ((g & 1) ? aB[3] : aB[2]) : ((g & 1) ? aB[1] : aB[0]);
    const float2 bb2 = *reinterpret_cast<const float2*>(b1 + 2 * d);
    {
      PairU s; s.u = mA;
      float hx = fmaxf(f16_lo(s.h) + bb2.x, 0.0f);
      float hy = fmaxf(f16_hi(s.h) + bb2.y, 0.0f);
      const uint32_t j0 = (uint32_t)nA * 128u + 2u * (uint32_t)d;
      hx = drop_elem(j0)      ? 0.0f : hx * 2.0f;
      hy = drop_elem(j0 + 1u) ? 0.0f : hy * 2.0f;
      HT[(2 * wid) * 68 + d] = pack_f16x2(hx, hy);
    }
    {
      PairU s; s.u = mB;
      float hx = fmaxf(f16_lo(s.h) + bb2.x, 0.0f);
      float hy = fmaxf(f16_hi(s.h) + bb2.y, 0.0f);
      const uint32_t j0 = (uint32_t)nB * 128u + 2u * (uint32_t)d;
      hx = drop_elem(j0)      ? 0.0f : hx * 2.0f;
      hy = drop_elem(j0 + 1u) ? 0.0f : hy * 2.0f;
      HT[(2 * wid + 1) * 68 + d] = pack_f16x2(hx, hy);
    }
    __syncthreads();

    const int quad = lane >> 4;
    const int mrow = lane & 15;
    const int ct   = wid;
    f32x4 acc = {0.f, 0.f, 0.f, 0.f};
#pragma unroll
    for (int kb = 0; kb < 4; ++kb) {
      FragU a;
      a.q = *reinterpret_cast<const uint4*>(&HT[(mrow & 7) * 68 + kb * 16 + quad * 4]);
      FragU b;
      b.q = *reinterpret_cast<const uint4*>(&WT[(ct * 16 + mrow) * 68 + kb * 16 + quad * 4]);
      acc = __builtin_amdgcn_mfma_f32_16x16x32_f16(a.f, b.f, acc, 0, 0, 0);
    }
#pragma unroll
    for (int r = 0; r < 4; ++r) {
      const float v = acc[r];
      const float vOdd = __shfl(v, lane | 1);
      const int rloc = quad * 4 + r;
      if ((lane & 1) == 0 && rloc < 8) {
        z2h[(size_t)(n0 + rloc) * 32 + ct * 8 + (mrow >> 1)] = pack_f16x2(v, vOdd);
      }
    }
  }

  grid_barrier(bar);

  // ---------------- P3: agg_out ----------------
  const int g8 = lane >> 3;
  const int f8 = lane & 7;
  for (int vb = bid; vb < 6250; vb += nb) {
    const int pp = vb * 4 + wid;
    const int nA = pp * 2, nB = pp * 2 + 1;

    const uint8_t* rowA = adjr + (size_t)nA * kRowB;
    const uint8_t* rowB = adjr + (size_t)nB * kRowB;
    const int vaA = *(const uint16_t*)(rowA + 4 + 2 * lane);
    const int vaB = *(const uint16_t*)(rowB + 4 + 2 * lane);
    int dA = __builtin_amdgcn_readfirstlane(*(const int*)rowA); if (dA > kCap) dA = kCap;
    int dB = __builtin_amdgcn_readfirstlane(*(const int*)rowB); if (dB > kCap) dB = kCap;
    const int dm = (dA > dB) ? dA : dB;

    uint32_t aA[4], aB[4];
    {
      const uint4* pa = (g8 == 0) ? reinterpret_cast<const uint4*>(z2h + (size_t)nA * 32) : zq;
      const uint4* pb = (g8 == 0) ? reinterpret_cast<const uint4*>(z2h + (size_t)nB * 32) : zq;
      const uint4 va = pa[f8];
      const uint4 vb2 = pb[f8];
      aA[0] = va.x; aA[1] = va.y; aA[2] = va.z; aA[3] = va.w;
      aB[0] = vb2.x; aB[1] = vb2.y; aB[2] = vb2.z; aB[3] = vb2.w;
    }

    for (int e = 0; e < dm; e += 16) {
      uint4 lA[2], lB[2];
#pragma unroll
      for (int j = 0; j < 2; ++j) {
        const int sl = e + j * 8 + g8;
        const int ia = __shfl(vaA, sl);
        const uint4* pa = (sl < dA) ? reinterpret_cast<const uint4*>(z2h + (size_t)ia * 32) : zq;
        lA[j] = pa[f8];
      }
#pragma unroll
      for (int j = 0; j < 2; ++j) {
        const int sl = e + j * 8 + g8;
        const int ib = __shfl(vaB, sl);
        const uint4* pb = (sl < dB) ? reinterpret_cast<const uint4*>(z2h + (size_t)ib * 32) : zq;
        lB[j] = pb[f8];
      }
#pragma unroll
      for (int j = 0; j < 2; ++j) {
        pk_acc(aA[0], lA[j].x); pk_acc(aA[1], lA[j].y);
        pk_acc(aA[2], lA[j].z); pk_acc(aA[3], lA[j].w);
        pk_acc(aB[0], lB[j].x); pk_acc(aB[1], lB[j].y);
        pk_acc(aB[2], lB[j].z); pk_acc(aB[3], lB[j].w);
      }
    }

#pragma unroll
    for (int c = 0; c < 4; ++c) {
      uint32_t t;
      t = (uint32_t)__shfl_xor((int)aA[c], 8);  pk_acc(aA[c], t);
      t = (uint32_t)__shfl_xor((int)aA[c], 16); pk_acc(aA[c], t);
      t = (uint32_t)__shfl_xor((int)aA[c], 32); pk_acc(aA[c], t);
      t = (uint32_t)__shfl_xor((int)aB[c], 8);  pk_acc(aB[c], t);
      t = (uint32_t)__shfl_xor((int)aB[c], 16); pk_acc(aB[c], t);
      t = (uint32_t)__shfl_xor((int)aB[c], 32); pk_acc(aB[c], t);
    }

    const int d = 4 * f8 + (g8 & 3);
    const uint32_t mA = (g8 & 2) ? ((g8 & 1) ? aA[3] : aA[2]) : ((g8 & 1) ? aA[1] : aA[0]);
    const uint32_t mB = (g8 & 2) ? ((g8 & 1) ? aB[3] : aB[2]) : ((g8 & 1) ? aB[1] : aB[0]);
    if (g8 < 4) {
      const float2 bb2 = *reinterpret_cast<const float2*>(b2 + 2 * d);
      PairU sA; sA.u = mA;
      float2 oA; oA.x = f16_lo(sA.h) + bb2.x; oA.y = f16_hi(sA.h) + bb2.y;
      *reinterpret_cast<float2*>(out + (size_t)nA * 64 + 2 * d) = oA;
      PairU sB; sB.u = mB;
      float2 oB; oB.x = f16_lo(sB.h) + bb2.x; oB.y = f16_hi(sB.h) + bb2.y;
      *reinterpret_cast<float2*>(out + (size_t)nB * 64 + 2 * d) = oB;
    }
  }
}

// ================== FALLBACK: verified r6 3-kernel path ==================
__global__ __launch_bounds__(256, 8) void k1_adj_w2t_gemm1(
    const float* __restrict__ x, const float* __restrict__ W1,
    const float* __restrict__ W2, uint32_t* __restrict__ W2T,
    const int* __restrict__ src, const int* __restrict__ dst,
    uint8_t* __restrict__ adjr, int E, int adjBlocks,
    uint32_t* __restrict__ z1h) {
  __shared__ uint32_t WT[64 * 64];

  if (blockIdx.x < adjBlocks) {
    const int base = blockIdx.x * 1024 + threadIdx.x;
    int d[4], s[4];
    bool ok[4];
#pragma unroll
    for (int j = 0; j < 4; ++j) {
      const int e = base + j * 256;
      ok[j] = (e < E);
      d[j] = ok[j] ? dst[e] : 0;
      s[j] = ok[j] ? src[e] : 0;
    }
    int slot[4];
#pragma unroll
    for (int j = 0; j < 4; ++j)
      slot[j] = ok[j] ? atomicAdd((int*)(adjr + (size_t)d[j] * kRowB), 1) : kCap;
#pragma unroll
    for (int j = 0; j < 4; ++j)
      if (ok[j] && slot[j] < kCap)
        *(uint16_t*)(adjr + (size_t)d[j] * kRowB + 4 + 2 * slot[j]) = (uint16_t)s[j];
    return;
  }

  if (blockIdx.x < adjBlocks + kW2TBlocks) {
    const int w = (blockIdx.x - adjBlocks) * 256 + threadIdx.x;
    const int n = w >> 6, i = w & 63;
    W2T[w] = pack_f16x2(W2[(size_t)(2 * i) * 64 + n], W2[(size_t)(2 * i + 1) * 64 + n]);
    return;
  }

  const int gb = blockIdx.x - adjBlocks - kW2TBlocks;
  const int cg = gb & 1;
  for (int v = threadIdx.x; v < 64 * 64; v += 256) {
    const int i  = v >> 6;
    const int nl = v & 63;
    const int kb = i >> 4, r = i & 15;
    const int quad_s = r >> 2, c = r & 3;
    const int ct = nl >> 4, mrow_s = nl & 15;
    const int n = cg * 64 + nl;
    WT[((ct * 4 + kb) * 4 + quad_s) * 64 + mrow_s * 4 + c] =
        pack_f16x2(W1[(size_t)(2 * i) * 128 + n], W1[(size_t)(2 * i + 1) * 128 + n]);
  }
  __syncthreads();

  const int lane = threadIdx.x & 63;
  const int wid  = threadIdx.x >> 6;
  const int rb   = (gb >> 1) * 4 + wid;
  if (rb >= 3125) return;
  const int n0   = rb * 16;
  const int quad = lane >> 4;
  const int mrow = lane & 15;

  const float* xp = x + (size_t)(n0 + mrow) * 128 + quad * 8;
  f32x4 acc[4] = {{0.f,0.f,0.f,0.f},{0.f,0.f,0.f,0.f},{0.f,0.f,0.f,0.f},{0.f,0.f,0.f,0.f}};

#pragma unroll
  for (int kb = 0; kb < 4; ++kb) {
    const float4 lo = *reinterpret_cast<const float4*>(xp + kb * 32);
    const float4 hi = *reinterpret_cast<const float4*>(xp + kb * 32 + 4);
    FragU a;
    a.q = make_uint4(pack_f16x2(lo.x, lo.y), pack_f16x2(lo.z, lo.w),
                     pack_f16x2(hi.x, hi.y), pack_f16x2(hi.z, hi.w));
#pragma unroll
    for (int ct = 0; ct < 4; ++ct) {
      FragU b;
      b.q = *reinterpret_cast<const uint4*>(&WT[((ct * 4 + kb) * 4 + quad) * 64 + mrow * 4]);
      acc[ct] = __builtin_amdgcn_mfma_f32_16x16x32_f16(a.f, b.f, acc[ct], 0, 0, 0);
    }
  }

#pragma unroll
  for (int ct = 0; ct < 4; ++ct) {
#pragma unroll
    for (int r = 0; r < 4; ++r) {
      const float v = acc[ct][r];
      const float vOdd = __shfl(v, lane | 1);
      if ((lane & 1) == 0) {
        const int row = n0 + quad * 4 + r;
        z1h[(size_t)row * 64 + cg * 32 + ct * 8 + (mrow >> 1)] = pack_f16x2(v, vOdd);
      }
    }
  }
}

__global__ __launch_bounds__(256, 8) void agg1_gemm2(
    const uint32_t* __restrict__ z1h, const uint8_t* __restrict__ adjr,
    const float* __restrict__ b1,
    const uint32_t* __restrict__ zpad, const uint32_t* __restrict__ W2T,
    uint32_t* __restrict__ z2h) {
  __shared__ uint32_t WT[64 * 68];
  __shared__ uint32_t HT[8 * 68];

  for (int v = threadIdx.x; v < 64 * 64; v += 256)
    WT[(v >> 6) * 68 + (v & 63)] = W2T[v];

  const int lane = threadIdx.x & 63;
  const int wid  = threadIdx.x >> 6;
  const int n0   = blockIdx.x * 8;
  const int nA = n0 + 2 * wid, nB = nA + 1;
  const int g  = lane >> 4;
  const int fl = lane & 15;

  const uint4* zq = reinterpret_cast<const uint4*>(zpad);

  const uint8_t* rowA = adjr + (size_t)nA * kRowB;
  const uint8_t* rowB = adjr + (size_t)nB * kRowB;
  const int vaA = *(const uint16_t*)(rowA + 4 + 2 * lane);
  const int vaB = *(const uint16_t*)(rowB + 4 + 2 * lane);
  int dA = __builtin_amdgcn_readfirstlane(*(const int*)rowA); if (dA > kCap) dA = kCap;
  int dB = __builtin_amdgcn_readfirstlane(*(const int*)rowB); if (dB > kCap) dB = kCap;
  const int dm = (dA > dB) ? dA : dB;

  uint32_t aA[4], aB[4];
  {
    const uint4* pa = (g == 0) ? reinterpret_cast<const uint4*>(z1h + (size_t)nA * 64) : zq;
    const uint4* pb = (g == 0) ? reinterpret_cast<const uint4*>(z1h + (size_t)nB * 64) : zq;
    const uint4 va = pa[fl];
    const uint4 vb = pb[fl];
    aA[0] = va.x; aA[1] = va.y; aA[2] = va.z; aA[3] = va.w;
    aB[0] = vb.x; aB[1] = vb.y; aB[2] = vb.z; aB[3] = vb.w;
  }

  for (int e = 0; e < dm; e += 16) {
    uint4 lA[4], lB[4];
#pragma unroll
    for (int j = 0; j < 4; ++j) {
      const int sl = e + j * 4 + g;
      const int ia = __shfl(vaA, sl);
      const uint4* pa = (sl < dA) ? reinterpret_cast<const uint4*>(z1h + (size_t)ia * 64) : zq;
      lA[j] = pa[fl];
    }
#pragma unroll
    for (int j = 0; j < 4; ++j) {
      const int sl = e + j * 4 + g;
      const int ib = __shfl(vaB, sl);
      const uint4* pb = (sl < dB) ? reinterpret_cast<const uint4*>(z1h + (size_t)ib * 64) : zq;
      lB[j] = pb[fl];
    }
#pragma unroll
    for (int j = 0; j < 4; ++j) {
      pk_acc(aA[0], lA[j].x); pk_acc(aA[1], lA[j].y);
      pk_acc(aA[2], lA[j].z); pk_acc(aA[3], lA[j].w);
      pk_acc(aB[0], lB[j].x); pk_acc(aB[1], lB[j].y);
      pk_acc(aB[2], lB[j].z); pk_acc(aB[3], lB[j].w);
    }
  }

#pragma unroll
  for (int c = 0; c < 4; ++c) {
    uint32_t t;
    t = (uint32_t)__shfl_xor((int)aA[c], 16); pk_acc(aA[c], t);
    t = (uint32_t)__shfl_xor((int)aA[c], 32); pk_acc(aA[c], t);
    t = (uint32_t)__shfl_xor((int)aB[c], 16); pk_acc(aB[c], t);
    t = (uint32_t)__shfl_xor((int)aB[c], 32); pk_acc(aB[c], t);
  }

  const int d = 4 * fl + g;
  const uint32_t mA = (g & 2) ? ((g & 1) ? aA[3] : aA[2]) : ((g & 1) ? aA[1] : aA[0]);
  const uint32_t mB = (g & 2) ? ((g & 1) ? aB[3] : aB[2]) : ((g & 1) ? aB[1] : aB[0]);
  const float2 bb2 = *reinterpret_cast<const float2*>(b1 + 2 * d);
  {
    PairU s; s.u = mA;
    float hx = fmaxf(f16_lo(s.h) + bb2.x, 0.0f);
    float hy = fmaxf(f16_hi(s.h) + bb2.y, 0.0f);
    const uint32_t j0 = (uint32_t)nA * 128u + 2u * (uint32_t)d;
    hx = drop_elem(j0)      ? 0.0f : hx * 2.0f;
    hy = drop_elem(j0 + 1u) ? 0.0f : hy * 2.0f;
    HT[(2 * wid) * 68 + d] = pack_f16x2(hx, hy);
  }
  {
    PairU s; s.u = mB;
    float hx = fmaxf(f16_lo(s.h) + bb2.x, 0.0f);
    float hy = fmaxf(f16_hi(s.h) + bb2.y, 0.0f);
    const uint32_t j0 = (uint32_t)nB * 128u + 2u * (uint32_t)d;
    hx = drop_elem(j0)      ? 0.0f : hx * 2.0f;
    hy = drop_elem(j0 + 1u) ? 0.0f : hy * 2.0f;
    HT[(2 * wid + 1) * 68 + d] = pack_f16x2(hx, hy);
  }
  __syncthreads();

  const int quad = lane >> 4;
  const int mrow = lane & 15;
  const int ct   = wid;
  f32x4 acc = {0.f, 0.f, 0.f, 0.f};
#pragma unroll
  for (int kb = 0; kb < 4; ++kb) {
    FragU a;
    a.q = *reinterpret_cast<const uint4*>(&HT[(mrow & 7) * 68 + kb * 16 + quad * 4]);
    FragU b;
    b.q = *reinterpret_cast<const uint4*>(&WT[(ct * 16 + mrow) * 68 + kb * 16 + quad * 4]);
    acc = __builtin_amdgcn_mfma_f32_16x16x32_f16(a.f, b.f, acc, 0, 0, 0);
  }
#pragma unroll
  for (int r = 0; r < 4; ++r) {
    const float v = acc[r];
    const float vOdd = __shfl(v, lane | 1);
    const int rloc = quad * 4 + r;
    if ((lane & 1) == 0 && rloc < 8) {
      z2h[(size_t)(n0 + rloc) * 32 + ct * 8 + (mrow >> 1)] = pack_f16x2(v, vOdd);
    }
  }
}

__global__ __launch_bounds__(256, 8) void agg_out(
    const uint32_t* __restrict__ z2h, const uint8_t* __restrict__ adjr,
    const float* __restrict__ b2,
    const uint32_t* __restrict__ zpad, float* __restrict__ out) {
  const int lane = threadIdx.x & 63;
  const int wid  = threadIdx.x >> 6;
  const int pp = blockIdx.x * 4 + wid;
  const int nA = pp * 2, nB = pp * 2 + 1;
  const int g8 = lane >> 3;
  const int f8 = lane & 7;

  const uint4* zq = reinterpret_cast<const uint4*>(zpad);

  const uint8_t* rowA = adjr + (size_t)nA * kRowB;
  const uint8_t* rowB = adjr + (size_t)nB * kRowB;
  const int vaA = *(const uint16_t*)(rowA + 4 + 2 * lane);
  const int vaB = *(const uint16_t*)(rowB + 4 + 2 * lane);
  int dA = __builtin_amdgcn_readfirstlane(*(const int*)rowA); if (dA > kCap) dA = kCap;
  int dB = __builtin_amdgcn_readfirstlane(*(const int*)rowB); if (dB > kCap) dB = kCap;
  const int dm = (dA > dB) ? dA : dB;

  uint32_t aA[4], aB[4];
  {
    const uint4* pa = (g8 == 0) ? reinterpret_cast<const uint4*>(z2h + (size_t)nA * 32) : zq;
    const uint4* pb = (g8 == 0) ? reinterpret_cast<const uint4*>(z2h + (size_t)nB * 32) : zq;
    const uint4 va = pa[f8];
    const uint4 vb = pb[f8];
    aA[0] = va.x; aA[1] = va.y; aA[2] = va.z; aA[3] = va.w;
    aB[0] = vb.x; aB[1] = vb.y; aB[2] = vb.z; aB[3] = vb.w;
  }

  for (int e = 0; e < dm; e += 16) {
    uint4 lA[2], lB[2];
#pragma unroll
    for (int j = 0; j < 2; ++j) {
      const int sl = e + j * 8 + g8;
      const int ia = __shfl(vaA, sl);
      const uint4* pa = (sl < dA) ? reinterpret_cast<const uint4*>(z2h + (size_t)ia * 32) : zq;
      lA[j] = pa[f8];
    }
#pragma unroll
    for (int j = 0; j < 2; ++j) {
      const int sl = e + j * 8 + g8;
      const int ib = __shfl(vaB, sl);
      const uint4* pb = (sl < dB) ? reinterpret_cast<const uint4*>(z2h + (size_t)ib * 32) : zq;
      lB[j] = pb[f8];
    }
#pragma unroll
    for (int j = 0; j < 2; ++j) {
      pk_acc(aA[0], lA[j].x); pk_acc(aA[1], lA[j].y);
      pk_acc(aA[2], lA[j].z); pk_acc(aA[3], lA[j].w);
      pk_acc(aB[0], lB[j].x); pk_acc(aB[1], lB[j].y);
      pk_acc(aB[2], lB[j].z); pk_acc(aB[3], lB[j].w);
    }
  }

#pragma unroll
  for (int c = 0; c < 4; ++c) {
    uint32_t t;
    t = (uint32_t)__shfl_xor((int)aA[c], 8);  pk_acc(aA[c], t);
    t = (uint32_t)__shfl_xor((int)aA[c], 16); pk_acc(aA[c], t);
    t = (uint32_t)__shfl_xor((int)aA[c], 32); pk_acc(aA[c], t);
    t = (uint32_t)__shfl_xor((int)aB[c], 8);  pk_acc(aB[c], t);
    t = (uint32_t)__shfl_xor((int)aB[c], 16); pk_acc(aB[c], t);
    t = (uint32_t)__shfl_xor((int)aB[c], 32); pk_acc(aB[c], t);
  }

  const int d = 4 * f8 + (g8 & 3);
  const uint32_t mA = (g8 & 2) ? ((g8 & 1) ? aA[3] : aA[2]) : ((g8 & 1) ? aA[1] : aA[0]);
  const uint32_t mB = (g8 & 2) ? ((g8 & 1) ? aB[3] : aB[2]) : ((g8 & 1) ? aB[1] : aB[0]);
  if (g8 < 4) {
    const float2 bb2 = *reinterpret_cast<const float2*>(b2 + 2 * d);
    PairU sA; sA.u = mA;
    float2 oA; oA.x = f16_lo(sA.h) + bb2.x; oA.y = f16_hi(sA.h) + bb2.y;
    *reinterpret_cast<float2*>(out + (size_t)nA * 64 + 2 * d) = oA;
    PairU sB; sB.u = mB;
    float2 oB; oB.x = f16_lo(sB.h) + bb2.x; oB.y = f16_hi(sB.h) + bb2.y;
    *reinterpret_cast<float2*>(out + (size_t)nB * 64 + 2 * d) = oB;
  }
}

// ---------------- launch ----------------
extern "C" void kernel_launch(void* const* d_in, const int* in_sizes, int n_in,
                              void* d_out, int out_size, void* d_ws, size_t ws_size,
                              hipStream_t stream) {
  const float* x  = (const float*)d_in[0];
  const int*   ei = (const int*)d_in[1];
  const float* W1 = (const float*)d_in[2];
  const float* b1 = (const float*)d_in[3];
  const float* W2 = (const float*)d_in[4];
  const float* b2 = (const float*)d_in[5];
  float* out = (float*)d_out;

  const int E = in_sizes[1] / 2;  // edge_index is (2, E), int32 on device
  const int* src = ei;
  const int* dst = ei + E;

  // d_ws layout:
  int*      bar  = (int*)d_ws;                             // 256 B barrier state (zeroed)
  uint32_t* zpad = (uint32_t*)d_ws + 64;                   // 256 B zero pad (zeroed)
  uint8_t*  adjr = (uint8_t*)d_ws + 512;                   // 50000 x 192 B = 9.6 MB (zeroed)
  uint32_t* z1h  = (uint32_t*)(adjr + (size_t)kN * kRowB); // 12.8 MB
  uint32_t* z2h  = z1h + (size_t)kN * 64;                  // 6.4 MB
  uint32_t* W2T  = z2h + (size_t)kN * 32;                  // 16 KB

  const int adjBlocks = (E + 1023) / 1024;  // 4 edges/thread

  // Co-residency-safe grid for the fused kernel (pure host queries, cached).
  static int fusedGrid = -2;
  if (fusedGrid == -2) {
    int dev = 0, numCU = 0, maxB = 0;
    if (hipGetDevice(&dev) == hipSuccess &&
        hipDeviceGetAttribute(&numCU, hipDeviceAttributeMultiprocessorCount, dev) == hipSuccess &&
        hipOccupancyMaxActiveBlocksPerMultiprocessor(&maxB, fused_gin, 256, 0) == hipSuccess &&
        maxB > 0 && numCU > 0) {
      long cap = (long)maxB * (long)numCU;
      fusedGrid = (int)(cap > 6250 ? 6250 : cap);
    } else {
      fusedGrid = -1;  // fall back to the 3-kernel path
    }
    (void)hipGetLastError();
  }

  hipMemsetAsync(d_ws, 0, 512 + (size_t)kN * kRowB, stream);  // bar + zpad + adjr

  if (fusedGrid > 0) {
    fused_gin<<<fusedGrid, 256, 0, stream>>>(
        x, W1, W2, W2T, src, dst, adjr, E, adjBlocks,
        z1h, b1, zpad, z2h, b2, out, bar);
  } else {
    k1_adj_w2t_gemm1<<<adjBlocks + kW2TBlocks + kGemm1Blocks, 256, 0, stream>>>(
        x, W1, W2, W2T, src, dst, adjr, E, adjBlocks, z1h);
    agg1_gemm2<<<6250, 256, 0, stream>>>(z1h, adjr, b1, zpad, W2T, z2h);
    agg_out<<<6250, 256, 0, stream>>>(z2h, adjr, b2, zpad, out);
  }
}

// Round 8
// 474.795 us; speedup vs baseline: 1.4389x; 1.4389x over previous
//
#include <hip/hip_runtime.h>
#include <hip/hip_cooperative_groups.h>
#include <stdint.h>

namespace cg = cooperative_groups;

static constexpr int kN   = 50000;   // nodes
static constexpr int kCap = 64;      // adjacency capacity per node (Poisson(12) tail @64 ~ 1e-25)
static constexpr int kRowB = 192;    // adjacency row bytes: [cnt:int][64 x u16 slots][pad] (3 lines)
static constexpr int kW2TBlocks = 16;    // 16*256 = 4096 = W2T dwords
static constexpr int kGemm1Blocks = 1564;  // 782 rb-groups x 2 cg

typedef __attribute__((ext_vector_type(8))) _Float16 f16x8;  // MFMA A/B fragment
typedef __attribute__((ext_vector_type(2))) _Float16 f16x2;  // packed pair -> v_pk_add_f16
typedef __attribute__((ext_vector_type(4))) float f32x4;     // MFMA 16x16 accumulator

// ---------------- threefry2x32-20 (verified vs Random123 KAT) ----------------
__device__ __forceinline__ uint32_t rotl32(uint32_t v, uint32_t r) {
  return (v << r) | (v >> (32u - r));
}

__device__ __forceinline__ uint2 threefry2x32(uint32_t k0, uint32_t k1,
                                              uint32_t x0, uint32_t x1) {
  const uint32_t k2 = k0 ^ k1 ^ 0x1BD11BDAu;
  x0 += k0; x1 += k1;
#define TFR(r) { x0 += x1; x1 = rotl32(x1, r); x1 ^= x0; }
  TFR(13u) TFR(15u) TFR(26u) TFR(6u)
  x0 += k1; x1 += k2 + 1u;
  TFR(17u) TFR(29u) TFR(16u) TFR(24u)
  x0 += k2; x1 += k0 + 2u;
  TFR(13u) TFR(15u) TFR(26u) TFR(6u)
  x0 += k0; x1 += k1 + 3u;
  TFR(17u) TFR(29u) TFR(16u) TFR(24u)
  x0 += k1; x1 += k2 + 4u;
  TFR(13u) TFR(15u) TFR(26u) TFR(6u)
  x0 += k2; x1 += k0 + 5u;
#undef TFR
  return make_uint2(x0, x1);
}

__device__ __forceinline__ bool drop_elem(uint32_t j) {
  const uint2 r = threefry2x32(0u, 42u, 0u, j);
  return ((r.x ^ r.y) >> 31) != 0u;
}

// ---------------- f16 pack/unpack ----------------
union PairU { f16x2 h; uint32_t u; };
__device__ __forceinline__ uint32_t pack_f16x2(float lo, float hi) {
  PairU p; p.h[0] = (_Float16)lo; p.h[1] = (_Float16)hi; return p.u;
}
__device__ __forceinline__ float f16_lo(f16x2 v) { return (float)v[0]; }
__device__ __forceinline__ float f16_hi(f16x2 v) { return (float)v[1]; }

__device__ __forceinline__ void pk_acc(uint32_t& acc, uint32_t v) {
  PairU a, b; a.u = acc; b.u = v; a.h += b.h; acc = a.u;
}

union FragU { uint4 q; f16x8 f; };

// ================== FUSED cooperative pipeline ==================
// P1: adj-build | W2T-pack | gemm1 (grid-stride over virtual blocks)
// P2: agg1 + gemm2 (grid-stride, 6250 tiles)
// P3: agg_out (grid-stride, 6250 tiles)
// Phase bodies byte-identical to the verified r6 kernels (172.2 us).
// Grid sync = cooperative_groups::this_grid().sync() (vendor-tuned; the r7
// hand-rolled acquire-polling barrier caused an L1/L2 invalidation storm).
__global__ __launch_bounds__(256, 8) void fused_gin(
    const float* __restrict__ x, const float* __restrict__ W1,
    const float* __restrict__ W2, uint32_t* __restrict__ W2T,
    const int* __restrict__ src, const int* __restrict__ dst,
    uint8_t* __restrict__ adjr, int E, int adjBlocks,
    uint32_t* __restrict__ z1h, const float* __restrict__ b1,
    const uint32_t* __restrict__ zpad, uint32_t* __restrict__ z2h,
    const float* __restrict__ b2, float* __restrict__ out) {
  __shared__ uint32_t LDS[64 * 68 + 8 * 68];  // 19.6 KB union (P1 uses first 16 KB)

  cg::grid_group grid = cg::this_grid();

  const int tid = threadIdx.x;
  const int bid = blockIdx.x;
  const int nb  = gridDim.x;
  const int lane = tid & 63;
  const int wid  = tid >> 6;

  // ---------------- P1 ----------------
  const int nVB1 = adjBlocks + kW2TBlocks + kGemm1Blocks;
  for (int vb = bid; vb < nVB1; vb += nb) {
    if (vb < adjBlocks) {
      const int base = vb * 1024 + tid;
      int d[4], s[4];
      bool ok[4];
#pragma unroll
      for (int j = 0; j < 4; ++j) {
        const int e = base + j * 256;
        ok[j] = (e < E);
        d[j] = ok[j] ? dst[e] : 0;
        s[j] = ok[j] ? src[e] : 0;
      }
      int slot[4];
#pragma unroll
      for (int j = 0; j < 4; ++j)
        slot[j] = ok[j] ? atomicAdd((int*)(adjr + (size_t)d[j] * kRowB), 1) : kCap;
#pragma unroll
      for (int j = 0; j < 4; ++j)
        if (ok[j] && slot[j] < kCap)
          *(uint16_t*)(adjr + (size_t)d[j] * kRowB + 4 + 2 * slot[j]) = (uint16_t)s[j];
    } else if (vb < adjBlocks + kW2TBlocks) {
      const int w = (vb - adjBlocks) * 256 + tid;  // < 4096
      const int n = w >> 6, i = w & 63;
      W2T[w] = pack_f16x2(W2[(size_t)(2 * i) * 64 + n], W2[(size_t)(2 * i + 1) * 64 + n]);
    } else {
      const int gb = vb - adjBlocks - kW2TBlocks;  // 0..1563
      const int cg2 = gb & 1;
      // Stage this cg's half of W1, fragment-major (conflict-free B-fragment reads).
      for (int v = tid; v < 64 * 64; v += 256) {
        const int i  = v >> 6;
        const int nl = v & 63;
        const int kb = i >> 4, r = i & 15;
        const int quad_s = r >> 2, c = r & 3;
        const int ct = nl >> 4, mrow_s = nl & 15;
        const int n = cg2 * 64 + nl;
        LDS[((ct * 4 + kb) * 4 + quad_s) * 64 + mrow_s * 4 + c] =
            pack_f16x2(W1[(size_t)(2 * i) * 128 + n], W1[(size_t)(2 * i + 1) * 128 + n]);
      }
      __syncthreads();
      const int rb = (gb >> 1) * 4 + wid;  // -> rb 0..3127
      if (rb < 3125) {
        const int n0   = rb * 16;
        const int quad = lane >> 4;
        const int mrow = lane & 15;
        const float* xp = x + (size_t)(n0 + mrow) * 128 + quad * 8;
        f32x4 acc[4] = {{0.f,0.f,0.f,0.f},{0.f,0.f,0.f,0.f},{0.f,0.f,0.f,0.f},{0.f,0.f,0.f,0.f}};
#pragma unroll
        for (int kb = 0; kb < 4; ++kb) {
          const float4 lo = *reinterpret_cast<const float4*>(xp + kb * 32);
          const float4 hi = *reinterpret_cast<const float4*>(xp + kb * 32 + 4);
          FragU a;
          a.q = make_uint4(pack_f16x2(lo.x, lo.y), pack_f16x2(lo.z, lo.w),
                           pack_f16x2(hi.x, hi.y), pack_f16x2(hi.z, hi.w));
#pragma unroll
          for (int ct = 0; ct < 4; ++ct) {
            FragU b;
            b.q = *reinterpret_cast<const uint4*>(&LDS[((ct * 4 + kb) * 4 + quad) * 64 + mrow * 4]);
            acc[ct] = __builtin_amdgcn_mfma_f32_16x16x32_f16(a.f, b.f, acc[ct], 0, 0, 0);
          }
        }
#pragma unroll
        for (int ct = 0; ct < 4; ++ct) {
#pragma unroll
          for (int r = 0; r < 4; ++r) {
            const float v = acc[ct][r];
            const float vOdd = __shfl(v, lane | 1);
            if ((lane & 1) == 0) {
              const int row = n0 + quad * 4 + r;
              z1h[(size_t)row * 64 + cg2 * 32 + ct * 8 + (mrow >> 1)] = pack_f16x2(v, vOdd);
            }
          }
        }
      }
      __syncthreads();  // WAR: protect LDS before next-iteration restage
    }
  }

  grid.sync();

  // ---------------- P2: agg1 + gemm2 ----------------
  uint32_t* WT = LDS;
  uint32_t* HT = LDS + 64 * 68;
  for (int v = tid; v < 64 * 64; v += 256)
    WT[(v >> 6) * 68 + (v & 63)] = W2T[v];

  const uint4* zq = reinterpret_cast<const uint4*>(zpad);
  const int g  = lane >> 4;
  const int fl = lane & 15;

  for (int vb = bid; vb < 6250; vb += nb) {
    __syncthreads();  // covers WT staging (1st iter) + HT WAR (later iters)
    const int n0 = vb * 8;
    const int nA = n0 + 2 * wid, nB = nA + 1;

    const uint8_t* rowA = adjr + (size_t)nA * kRowB;
    const uint8_t* rowB = adjr + (size_t)nB * kRowB;
    const int vaA = *(const uint16_t*)(rowA + 4 + 2 * lane);
    const int vaB = *(const uint16_t*)(rowB + 4 + 2 * lane);
    int dA = __builtin_amdgcn_readfirstlane(*(const int*)rowA); if (dA > kCap) dA = kCap;
    int dB = __builtin_amdgcn_readfirstlane(*(const int*)rowB); if (dB > kCap) dB = kCap;
    const int dm = (dA > dB) ? dA : dB;

    uint32_t aA[4], aB[4];
    {
      const uint4* pa = (g == 0) ? reinterpret_cast<const uint4*>(z1h + (size_t)nA * 64) : zq;
      const uint4* pb = (g == 0) ? reinterpret_cast<const uint4*>(z1h + (size_t)nB * 64) : zq;
      const uint4 va = pa[fl];
      const uint4 vb2 = pb[fl];
      aA[0] = va.x; aA[1] = va.y; aA[2] = va.z; aA[3] = va.w;
      aB[0] = vb2.x; aB[1] = vb2.y; aB[2] = vb2.z; aB[3] = vb2.w;
    }

    for (int e = 0; e < dm; e += 16) {
      uint4 lA[4], lB[4];
#pragma unroll
      for (int j = 0; j < 4; ++j) {
        const int sl = e + j * 4 + g;
        const int ia = __shfl(vaA, sl);
        const uint4* pa = (sl < dA) ? reinterpret_cast<const uint4*>(z1h + (size_t)ia * 64) : zq;
        lA[j] = pa[fl];
      }
#pragma unroll
      for (int j = 0; j < 4; ++j) {
        const int sl = e + j * 4 + g;
        const int ib = __shfl(vaB, sl);
        const uint4* pb = (sl < dB) ? reinterpret_cast<const uint4*>(z1h + (size_t)ib * 64) : zq;
        lB[j] = pb[fl];
      }
#pragma unroll
      for (int j = 0; j < 4; ++j) {
        pk_acc(aA[0], lA[j].x); pk_acc(aA[1], lA[j].y);
        pk_acc(aA[2], lA[j].z); pk_acc(aA[3], lA[j].w);
        pk_acc(aB[0], lB[j].x); pk_acc(aB[1], lB[j].y);
        pk_acc(aB[2], lB[j].z); pk_acc(aB[3], lB[j].w);
      }
    }

#pragma unroll
    for (int c = 0; c < 4; ++c) {
      uint32_t t;
      t = (uint32_t)__shfl_xor((int)aA[c], 16); pk_acc(aA[c], t);
      t = (uint32_t)__shfl_xor((int)aA[c], 32); pk_acc(aA[c], t);
      t = (uint32_t)__shfl_xor((int)aB[c], 16); pk_acc(aB[c], t);
      t = (uint32_t)__shfl_xor((int)aB[c], 32); pk_acc(aB[c], t);
    }

    const int d = 4 * fl + g;
    const uint32_t mA = (g & 2) ? ((g & 1) ? aA[3] : aA[2]) : ((g & 1) ? aA[1] : aA[0]);
    const uint32_t mB = (g & 2) ? ((g & 1) ? aB[3] : aB[2]) : ((g & 1) ? aB[1] : aB[0]);
    const float2 bb2 = *reinterpret_cast<const float2*>(b1 + 2 * d);
    {
      PairU s; s.u = mA;
      float hx = fmaxf(f16_lo(s.h) + bb2.x, 0.0f);
      float hy = fmaxf(f16_hi(s.h) + bb2.y, 0.0f);
      const uint32_t j0 = (uint32_t)nA * 128u + 2u * (uint32_t)d;
      hx = drop_elem(j0)      ? 0.0f : hx * 2.0f;
      hy = drop_elem(j0 + 1u) ? 0.0f : hy * 2.0f;
      HT[(2 * wid) * 68 + d] = pack_f16x2(hx, hy);
    }
    {
      PairU s; s.u = mB;
      float hx = fmaxf(f16_lo(s.h) + bb2.x, 0.0f);
      float hy = fmaxf(f16_hi(s.h) + bb2.y, 0.0f);
      const uint32_t j0 = (uint32_t)nB * 128u + 2u * (uint32_t)d;
      hx = drop_elem(j0)      ? 0.0f : hx * 2.0f;
      hy = drop_elem(j0 + 1u) ? 0.0f : hy * 2.0f;
      HT[(2 * wid + 1) * 68 + d] = pack_f16x2(hx, hy);
    }
    __syncthreads();

    const int quad = lane >> 4;
    const int mrow = lane & 15;
    const int ct   = wid;
    f32x4 acc = {0.f, 0.f, 0.f, 0.f};
#pragma unroll
    for (int kb = 0; kb < 4; ++kb) {
      FragU a;
      a.q = *reinterpret_cast<const uint4*>(&HT[(mrow & 7) * 68 + kb * 16 + quad * 4]);
      FragU b;
      b.q = *reinterpret_cast<const uint4*>(&WT[(ct * 16 + mrow) * 68 + kb * 16 + quad * 4]);
      acc = __builtin_amdgcn_mfma_f32_16x16x32_f16(a.f, b.f, acc, 0, 0, 0);
    }
#pragma unroll
    for (int r = 0; r < 4; ++r) {
      const float v = acc[r];
      const float vOdd = __shfl(v, lane | 1);
      const int rloc = quad * 4 + r;
      if ((lane & 1) == 0 && rloc < 8) {
        z2h[(size_t)(n0 + rloc) * 32 + ct * 8 + (mrow >> 1)] = pack_f16x2(v, vOdd);
      }
    }
  }

  grid.sync();

  // ---------------- P3: agg_out ----------------
  const int g8 = lane >> 3;
  const int f8 = lane & 7;
  for (int vb = bid; vb < 6250; vb += nb) {
    const int pp = vb * 4 + wid;
    const int nA = pp * 2, nB = pp * 2 + 1;

    const uint8_t* rowA = adjr + (size_t)nA * kRowB;
    const uint8_t* rowB = adjr + (size_t)nB * kRowB;
    const int vaA = *(const uint16_t*)(rowA + 4 + 2 * lane);
    const int vaB = *(const uint16_t*)(rowB + 4 + 2 * lane);
    int dA = __builtin_amdgcn_readfirstlane(*(const int*)rowA); if (dA > kCap) dA = kCap;
    int dB = __builtin_amdgcn_readfirstlane(*(const int*)rowB); if (dB > kCap) dB = kCap;
    const int dm = (dA > dB) ? dA : dB;

    uint32_t aA[4], aB[4];
    {
      const uint4* pa = (g8 == 0) ? reinterpret_cast<const uint4*>(z2h + (size_t)nA * 32) : zq;
      const uint4* pb = (g8 == 0) ? reinterpret_cast<const uint4*>(z2h + (size_t)nB * 32) : zq;
      const uint4 va = pa[f8];
      const uint4 vb2 = pb[f8];
      aA[0] = va.x; aA[1] = va.y; aA[2] = va.z; aA[3] = va.w;
      aB[0] = vb2.x; aB[1] = vb2.y; aB[2] = vb2.z; aB[3] = vb2.w;
    }

    for (int e = 0; e < dm; e += 16) {
      uint4 lA[2], lB[2];
#pragma unroll
      for (int j = 0; j < 2; ++j) {
        const int sl = e + j * 8 + g8;
        const int ia = __shfl(vaA, sl);
        const uint4* pa = (sl < dA) ? reinterpret_cast<const uint4*>(z2h + (size_t)ia * 32) : zq;
        lA[j] = pa[f8];
      }
#pragma unroll
      for (int j = 0; j < 2; ++j) {
        const int sl = e + j * 8 + g8;
        const int ib = __shfl(vaB, sl);
        const uint4* pb = (sl < dB) ? reinterpret_cast<const uint4*>(z2h + (size_t)ib * 32) : zq;
        lB[j] = pb[f8];
      }
#pragma unroll
      for (int j = 0; j < 2; ++j) {
        pk_acc(aA[0], lA[j].x); pk_acc(aA[1], lA[j].y);
        pk_acc(aA[2], lA[j].z); pk_acc(aA[3], lA[j].w);
        pk_acc(aB[0], lB[j].x); pk_acc(aB[1], lB[j].y);
        pk_acc(aB[2], lB[j].z); pk_acc(aB[3], lB[j].w);
      }
    }

#pragma unroll
    for (int c = 0; c < 4; ++c) {
      uint32_t t;
      t = (uint32_t)__shfl_xor((int)aA[c], 8);  pk_acc(aA[c], t);
      t = (uint32_t)__shfl_xor((int)aA[c], 16); pk_acc(aA[c], t);
      t = (uint32_t)__shfl_xor((int)aA[c], 32); pk_acc(aA[c], t);
      t = (uint32_t)__shfl_xor((int)aB[c], 8);  pk_acc(aB[c], t);
      t = (uint32_t)__shfl_xor((int)aB[c], 16); pk_acc(aB[c], t);
      t = (uint32_t)__shfl_xor((int)aB[c], 32); pk_acc(aB[c], t);
    }

    const int d = 4 * f8 + (g8 & 3);
    const uint32_t mA = (g8 & 2) ? ((g8 & 1) ? aA[3] : aA[2]) : ((g8 & 1) ? aA[1] : aA[0]);
    const uint32_t mB = (g8 & 2) ? ((g8 & 1) ? aB[3] : aB[2]) : ((g8 & 1) ? aB[1] : aB[0]);
    if (g8 < 4) {
      const float2 bb2 = *reinterpret_cast<const float2*>(b2 + 2 * d);
      PairU sA; sA.u = mA;
      float2 oA; oA.x = f16_lo(sA.h) + bb2.x; oA.y = f16_hi(sA.h) + bb2.y;
      *reinterpret_cast<float2*>(out + (size_t)nA * 64 + 2 * d) = oA;
      PairU sB; sB.u = mB;
      float2 oB; oB.x = f16_lo(sB.h) + bb2.x; oB.y = f16_hi(sB.h) + bb2.y;
      *reinterpret_cast<float2*>(out + (size_t)nB * 64 + 2 * d) = oB;
    }
  }
}

// ================== FALLBACK: verified r6 3-kernel path ==================
__global__ __launch_bounds__(256, 8) void k1_adj_w2t_gemm1(
    const float* __restrict__ x, const float* __restrict__ W1,
    const float* __restrict__ W2, uint32_t* __restrict__ W2T,
    const int* __restrict__ src, const int* __restrict__ dst,
    uint8_t* __restrict__ adjr, int E, int adjBlocks,
    uint32_t* __restrict__ z1h) {
  __shared__ uint32_t WT[64 * 64];

  if (blockIdx.x < adjBlocks) {
    const int base = blockIdx.x * 1024 + threadIdx.x;
    int d[4], s[4];
    bool ok[4];
#pragma unroll
    for (int j = 0; j < 4; ++j) {
      const int e = base + j * 256;
      ok[j] = (e < E);
      d[j] = ok[j] ? dst[e] : 0;
      s[j] = ok[j] ? src[e] : 0;
    }
    int slot[4];
#pragma unroll
    for (int j = 0; j < 4; ++j)
      slot[j] = ok[j] ? atomicAdd((int*)(adjr + (size_t)d[j] * kRowB), 1) : kCap;
#pragma unroll
    for (int j = 0; j < 4; ++j)
      if (ok[j] && slot[j] < kCap)
        *(uint16_t*)(adjr + (size_t)d[j] * kRowB + 4 + 2 * slot[j]) = (uint16_t)s[j];
    return;
  }

  if (blockIdx.x < adjBlocks + kW2TBlocks) {
    const int w = (blockIdx.x - adjBlocks) * 256 + threadIdx.x;
    const int n = w >> 6, i = w & 63;
    W2T[w] = pack_f16x2(W2[(size_t)(2 * i) * 64 + n], W2[(size_t)(2 * i + 1) * 64 + n]);
    return;
  }

  const int gb = blockIdx.x - adjBlocks - kW2TBlocks;
  const int cg2 = gb & 1;
  for (int v = threadIdx.x; v < 64 * 64; v += 256) {
    const int i  = v >> 6;
    const int nl = v & 63;
    const int kb = i >> 4, r = i & 15;
    const int quad_s = r >> 2, c = r & 3;
    const int ct = nl >> 4, mrow_s = nl & 15;
    const int n = cg2 * 64 + nl;
    WT[((ct * 4 + kb) * 4 + quad_s) * 64 + mrow_s * 4 + c] =
        pack_f16x2(W1[(size_t)(2 * i) * 128 + n], W1[(size_t)(2 * i + 1) * 128 + n]);
  }
  __syncthreads();

  const int lane = threadIdx.x & 63;
  const int wid  = threadIdx.x >> 6;
  const int rb   = (gb >> 1) * 4 + wid;
  if (rb >= 3125) return;
  const int n0   = rb * 16;
  const int quad = lane >> 4;
  const int mrow = lane & 15;

  const float* xp = x + (size_t)(n0 + mrow) * 128 + quad * 8;
  f32x4 acc[4] = {{0.f,0.f,0.f,0.f},{0.f,0.f,0.f,0.f},{0.f,0.f,0.f,0.f},{0.f,0.f,0.f,0.f}};

#pragma unroll
  for (int kb = 0; kb < 4; ++kb) {
    const float4 lo = *reinterpret_cast<const float4*>(xp + kb * 32);
    const float4 hi = *reinterpret_cast<const float4*>(xp + kb * 32 + 4);
    FragU a;
    a.q = make_uint4(pack_f16x2(lo.x, lo.y), pack_f16x2(lo.z, lo.w),
                     pack_f16x2(hi.x, hi.y), pack_f16x2(hi.z, hi.w));
#pragma unroll
    for (int ct = 0; ct < 4; ++ct) {
      FragU b;
      b.q = *reinterpret_cast<const uint4*>(&WT[((ct * 4 + kb) * 4 + quad) * 64 + mrow * 4]);
      acc[ct] = __builtin_amdgcn_mfma_f32_16x16x32_f16(a.f, b.f, acc[ct], 0, 0, 0);
    }
  }

#pragma unroll
  for (int ct = 0; ct < 4; ++ct) {
#pragma unroll
    for (int r = 0; r < 4; ++r) {
      const float v = acc[ct][r];
      const float vOdd = __shfl(v, lane | 1);
      if ((lane & 1) == 0) {
        const int row = n0 + quad * 4 + r;
        z1h[(size_t)row * 64 + cg2 * 32 + ct * 8 + (mrow >> 1)] = pack_f16x2(v, vOdd);
      }
    }
  }
}

__global__ __launch_bounds__(256, 8) void agg1_gemm2(
    const uint32_t* __restrict__ z1h, const uint8_t* __restrict__ adjr,
    const float* __restrict__ b1,
    const uint32_t* __restrict__ zpad, const uint32_t* __restrict__ W2T,
    uint32_t* __restrict__ z2h) {
  __shared__ uint32_t WT[64 * 68];
  __shared__ uint32_t HT[8 * 68];

  for (int v = threadIdx.x; v < 64 * 64; v += 256)
    WT[(v >> 6) * 68 + (v & 63)] = W2T[v];

  const int lane = threadIdx.x & 63;
  const int wid  = threadIdx.x >> 6;
  const int n0   = blockIdx.x * 8;
  const int nA = n0 + 2 * wid, nB = nA + 1;
  const int g  = lane >> 4;
  const int fl = lane & 15;

  const uint4* zq = reinterpret_cast<const uint4*>(zpad);

  const uint8_t* rowA = adjr + (size_t)nA * kRowB;
  const uint8_t* rowB = adjr + (size_t)nB * kRowB;
  const int vaA = *(const uint16_t*)(rowA + 4 + 2 * lane);
  const int vaB = *(const uint16_t*)(rowB + 4 + 2 * lane);
  int dA = __builtin_amdgcn_readfirstlane(*(const int*)rowA); if (dA > kCap) dA = kCap;
  int dB = __builtin_amdgcn_readfirstlane(*(const int*)rowB); if (dB > kCap) dB = kCap;
  const int dm = (dA > dB) ? dA : dB;

  uint32_t aA[4], aB[4];
  {
    const uint4* pa = (g == 0) ? reinterpret_cast<const uint4*>(z1h + (size_t)nA * 64) : zq;
    const uint4* pb = (g == 0) ? reinterpret_cast<const uint4*>(z1h + (size_t)nB * 64) : zq;
    const uint4 va = pa[fl];
    const uint4 vb = pb[fl];
    aA[0] = va.x; aA[1] = va.y; aA[2] = va.z; aA[3] = va.w;
    aB[0] = vb.x; aB[1] = vb.y; aB[2] = vb.z; aB[3] = vb.w;
  }

  for (int e = 0; e < dm; e += 16) {
    uint4 lA[4], lB[4];
#pragma unroll
    for (int j = 0; j < 4; ++j) {
      const int sl = e + j * 4 + g;
      const int ia = __shfl(vaA, sl);
      const uint4* pa = (sl < dA) ? reinterpret_cast<const uint4*>(z1h + (size_t)ia * 64) : zq;
      lA[j] = pa[fl];
    }
#pragma unroll
    for (int j = 0; j < 4; ++j) {
      const int sl = e + j * 4 + g;
      const int ib = __shfl(vaB, sl);
      const uint4* pb = (sl < dB) ? reinterpret_cast<const uint4*>(z1h + (size_t)ib * 64) : zq;
      lB[j] = pb[fl];
    }
#pragma unroll
    for (int j = 0; j < 4; ++j) {
      pk_acc(aA[0], lA[j].x); pk_acc(aA[1], lA[j].y);
      pk_acc(aA[2], lA[j].z); pk_acc(aA[3], lA[j].w);
      pk_acc(aB[0], lB[j].x); pk_acc(aB[1], lB[j].y);
      pk_acc(aB[2], lB[j].z); pk_acc(aB[3], lB[j].w);
    }
  }

#pragma unroll
  for (int c = 0; c < 4; ++c) {
    uint32_t t;
    t = (uint32_t)__shfl_xor((int)aA[c], 16); pk_acc(aA[c], t);
    t = (uint32_t)__shfl_xor((int)aA[c], 32); pk_acc(aA[c], t);
    t = (uint32_t)__shfl_xor((int)aB[c], 16); pk_acc(aB[c], t);
    t = (uint32_t)__shfl_xor((int)aB[c], 32); pk_acc(aB[c], t);
  }

  const int d = 4 * fl + g;
  const uint32_t mA = (g & 2) ? ((g & 1) ? aA[3] : aA[2]) : ((g & 1) ? aA[1] : aA[0]);
  const uint32_t mB = (g & 2) ? ((g & 1) ? aB[3] : aB[2]) : ((g & 1) ? aB[1] : aB[0]);
  const float2 bb2 = *reinterpret_cast<const float2*>(b1 + 2 * d);
  {
    PairU s; s.u = mA;
    float hx = fmaxf(f16_lo(s.h) + bb2.x, 0.0f);
    float hy = fmaxf(f16_hi(s.h) + bb2.y, 0.0f);
    const uint32_t j0 = (uint32_t)nA * 128u + 2u * (uint32_t)d;
    hx = drop_elem(j0)      ? 0.0f : hx * 2.0f;
    hy = drop_elem(j0 + 1u) ? 0.0f : hy * 2.0f;
    HT[(2 * wid) * 68 + d] = pack_f16x2(hx, hy);
  }
  {
    PairU s; s.u = mB;
    float hx = fmaxf(f16_lo(s.h) + bb2.x, 0.0f);
    float hy = fmaxf(f16_hi(s.h) + bb2.y, 0.0f);
    const uint32_t j0 = (uint32_t)nB * 128u + 2u * (uint32_t)d;
    hx = drop_elem(j0)      ? 0.0f : hx * 2.0f;
    hy = drop_elem(j0 + 1u) ? 0.0f : hy * 2.0f;
    HT[(2 * wid + 1) * 68 + d] = pack_f16x2(hx, hy);
  }
  __syncthreads();

  const int quad = lane >> 4;
  const int mrow = lane & 15;
  const int ct   = wid;
  f32x4 acc = {0.f, 0.f, 0.f, 0.f};
#pragma unroll
  for (int kb = 0; kb < 4; ++kb) {
    FragU a;
    a.q = *reinterpret_cast<const uint4*>(&HT[(mrow & 7) * 68 + kb * 16 + quad * 4]);
    FragU b;
    b.q = *reinterpret_cast<const uint4*>(&WT[(ct * 16 + mrow) * 68 + kb * 16 + quad * 4]);
    acc = __builtin_amdgcn_mfma_f32_16x16x32_f16(a.f, b.f, acc, 0, 0, 0);
  }
#pragma unroll
  for (int r = 0; r < 4; ++r) {
    const float v = acc[r];
    const float vOdd = __shfl(v, lane | 1);
    const int rloc = quad * 4 + r;
    if ((lane & 1) == 0 && rloc < 8) {
      z2h[(size_t)(n0 + rloc) * 32 + ct * 8 + (mrow >> 1)] = pack_f16x2(v, vOdd);
    }
  }
}

__global__ __launch_bounds__(256, 8) void agg_out(
    const uint32_t* __restrict__ z2h, const uint8_t* __restrict__ adjr,
    const float* __restrict__ b2,
    const uint32_t* __restrict__ zpad, float* __restrict__ out) {
  const int lane = threadIdx.x & 63;
  const int wid  = threadIdx.x >> 6;
  const int pp = blockIdx.x * 4 + wid;
  const int nA = pp * 2, nB = pp * 2 + 1;
  const int g8 = lane >> 3;
  const int f8 = lane & 7;

  const uint4* zq = reinterpret_cast<const uint4*>(zpad);

  const uint8_t* rowA = adjr + (size_t)nA * kRowB;
  const uint8_t* rowB = adjr + (size_t)nB * kRowB;
  const int vaA = *(const uint16_t*)(rowA + 4 + 2 * lane);
  const int vaB = *(const uint16_t*)(rowB + 4 + 2 * lane);
  int dA = __builtin_amdgcn_readfirstlane(*(const int*)rowA); if (dA > kCap) dA = kCap;
  int dB = __builtin_amdgcn_readfirstlane(*(const int*)rowB); if (dB > kCap) dB = kCap;
  const int dm = (dA > dB) ? dA : dB;

  uint32_t aA[4], aB[4];
  {
    const uint4* pa = (g8 == 0) ? reinterpret_cast<const uint4*>(z2h + (size_t)nA * 32) : zq;
    const uint4* pb = (g8 == 0) ? reinterpret_cast<const uint4*>(z2h + (size_t)nB * 32) : zq;
    const uint4 va = pa[f8];
    const uint4 vb = pb[f8];
    aA[0] = va.x; aA[1] = va.y; aA[2] = va.z; aA[3] = va.w;
    aB[0] = vb.x; aB[1] = vb.y; aB[2] = vb.z; aB[3] = vb.w;
  }

  for (int e = 0; e < dm; e += 16) {
    uint4 lA[2], lB[2];
#pragma unroll
    for (int j = 0; j < 2; ++j) {
      const int sl = e + j * 8 + g8;
      const int ia = __shfl(vaA, sl);
      const uint4* pa = (sl < dA) ? reinterpret_cast<const uint4*>(z2h + (size_t)ia * 32) : zq;
      lA[j] = pa[f8];
    }
#pragma unroll
    for (int j = 0; j < 2; ++j) {
      const int sl = e + j * 8 + g8;
      const int ib = __shfl(vaB, sl);
      const uint4* pb = (sl < dB) ? reinterpret_cast<const uint4*>(z2h + (size_t)ib * 32) : zq;
      lB[j] = pb[f8];
    }
#pragma unroll
    for (int j = 0; j < 2; ++j) {
      pk_acc(aA[0], lA[j].x); pk_acc(aA[1], lA[j].y);
      pk_acc(aA[2], lA[j].z); pk_acc(aA[3], lA[j].w);
      pk_acc(aB[0], lB[j].x); pk_acc(aB[1], lB[j].y);
      pk_acc(aB[2], lB[j].z); pk_acc(aB[3], lB[j].w);
    }
  }

#pragma unroll
  for (int c = 0; c < 4; ++c) {
    uint32_t t;
    t = (uint32_t)__shfl_xor((int)aA[c], 8);  pk_acc(aA[c], t);
    t = (uint32_t)__shfl_xor((int)aA[c], 16); pk_acc(aA[c], t);
    t = (uint32_t)__shfl_xor((int)aA[c], 32); pk_acc(aA[c], t);
    t = (uint32_t)__shfl_xor((int)aB[c], 8);  pk_acc(aB[c], t);
    t = (uint32_t)__shfl_xor((int)aB[c], 16); pk_acc(aB[c], t);
    t = (uint32_t)__shfl_xor((int)aB[c], 32); pk_acc(aB[c], t);
  }

  const int d = 4 * f8 + (g8 & 3);
  const uint32_t mA = (g8 & 2) ? ((g8 & 1) ? aA[3] : aA[2]) : ((g8 & 1) ? aA[1] : aA[0]);
  const uint32_t mB = (g8 & 2) ? ((g8 & 1) ? aB[3] : aB[2]) : ((g8 & 1) ? aB[1] : aB[0]);
  if (g8 < 4) {
    const float2 bb2 = *reinterpret_cast<const float2*>(b2 + 2 * d);
    PairU sA; sA.u = mA;
    float2 oA; oA.x = f16_lo(sA.h) + bb2.x; oA.y = f16_hi(sA.h) + bb2.y;
    *reinterpret_cast<float2*>(out + (size_t)nA * 64 + 2 * d) = oA;
    PairU sB; sB.u = mB;
    float2 oB; oB.x = f16_lo(sB.h) + bb2.x; oB.y = f16_hi(sB.h) + bb2.y;
    *reinterpret_cast<float2*>(out + (size_t)nB * 64 + 2 * d) = oB;
  }
}

// ---------------- launch ----------------
extern "C" void kernel_launch(void* const* d_in, const int* in_sizes, int n_in,
                              void* d_out, int out_size, void* d_ws, size_t ws_size,
                              hipStream_t stream) {
  const float* x  = (const float*)d_in[0];
  const int*   ei = (const int*)d_in[1];
  const float* W1 = (const float*)d_in[2];
  const float* b1 = (const float*)d_in[3];
  const float* W2 = (const float*)d_in[4];
  const float* b2 = (const float*)d_in[5];
  float* out = (float*)d_out;

  int E = in_sizes[1] / 2;  // edge_index is (2, E), int32 on device
  const int* src = ei;
  const int* dst = ei + E;

  // d_ws layout:
  uint32_t* zpad = (uint32_t*)d_ws + 64;                   // 256 B zero pad (zeroed)
  uint8_t*  adjr = (uint8_t*)d_ws + 512;                   // 50000 x 192 B = 9.6 MB (zeroed)
  uint32_t* z1h  = (uint32_t*)(adjr + (size_t)kN * kRowB); // 12.8 MB
  uint32_t* z2h  = z1h + (size_t)kN * 64;                  // 6.4 MB
  uint32_t* W2T  = z2h + (size_t)kN * 32;                  // 16 KB

  int adjBlocks = (E + 1023) / 1024;  // 4 edges/thread

  // Cooperative-launch gate (pure host queries, cached).
  static int coopGrid = -2;
  if (coopGrid == -2) {
    int dev = 0, coop = 0, numCU = 0, maxB = 0;
    if (hipGetDevice(&dev) == hipSuccess &&
        hipDeviceGetAttribute(&coop, hipDeviceAttributeCooperativeLaunch, dev) == hipSuccess &&
        coop != 0 &&
        hipDeviceGetAttribute(&numCU, hipDeviceAttributeMultiprocessorCount, dev) == hipSuccess &&
        hipOccupancyMaxActiveBlocksPerMultiprocessor(&maxB, fused_gin, 256, 0) == hipSuccess &&
        maxB > 0 && numCU > 0) {
      long cap = (long)maxB * (long)numCU;
      coopGrid = (int)(cap > 6250 ? 6250 : cap);
    } else {
      coopGrid = -1;  // fall back to the 3-kernel path
    }
    (void)hipGetLastError();
  }

  hipMemsetAsync(d_ws, 0, 512 + (size_t)kN * kRowB, stream);  // zpad + adjr (cnt=0)

  bool launched = false;
  if (coopGrid > 0) {
    void* args[] = {(void*)&x,   (void*)&W1,  (void*)&W2,  (void*)&W2T,
                    (void*)&src, (void*)&dst, (void*)&adjr, (void*)&E,
                    (void*)&adjBlocks, (void*)&z1h, (void*)&b1, (void*)&zpad,
                    (void*)&z2h, (void*)&b2,  (void*)&out};
    hipError_t err = hipLaunchCooperativeKernel(
        reinterpret_cast<void*>(fused_gin), dim3(coopGrid), dim3(256), args, 0, stream);
    if (err == hipSuccess) {
      launched = true;
    } else {
      coopGrid = -1;  // never retry; fall through to the verified path
      (void)hipGetLastError();
    }
  }

  if (!launched) {
    k1_adj_w2t_gemm1<<<adjBlocks + kW2TBlocks + kGemm1Blocks, 256, 0, stream>>>(
        x, W1, W2, W2T, src, dst, adjr, E, adjBlocks, z1h);
    agg1_gemm2<<<6250, 256, 0, stream>>>(z1h, adjr, b1, zpad, W2T, z2h);
    agg_out<<<6250, 256, 0, stream>>>(z2h, adjr, b2, zpad, out);
  }
}

// Round 9
// 170.469 us; speedup vs baseline: 4.0077x; 2.7852x over previous
//
#include <hip/hip_runtime.h>
#include <stdint.h>

static constexpr int kN   = 50000;   // nodes
static constexpr int kCap = 64;      // adjacency capacity per node (Poisson(12) tail @64 ~ 1e-25)
static constexpr int kRowB = 192;    // adjacency row bytes: [cnt:int][64 x u16 slots][pad] (3 lines)
static constexpr int kW2TBlocks = 16;    // 16*256 = 4096 = W2T dwords
static constexpr int kGemm1Blocks = 1564;  // 782 rb-groups x 2 cg

typedef __attribute__((ext_vector_type(8))) _Float16 f16x8;  // MFMA A/B fragment
typedef __attribute__((ext_vector_type(2))) _Float16 f16x2;  // packed pair -> v_pk_add_f16
typedef __attribute__((ext_vector_type(4))) float f32x4;     // MFMA 16x16 accumulator

// ---------------- threefry2x32-20 (verified vs Random123 KAT) ----------------
__device__ __forceinline__ uint32_t rotl32(uint32_t v, uint32_t r) {
  return (v << r) | (v >> (32u - r));
}

__device__ __forceinline__ uint2 threefry2x32(uint32_t k0, uint32_t k1,
                                              uint32_t x0, uint32_t x1) {
  const uint32_t k2 = k0 ^ k1 ^ 0x1BD11BDAu;
  x0 += k0; x1 += k1;
#define TFR(r) { x0 += x1; x1 = rotl32(x1, r); x1 ^= x0; }
  TFR(13u) TFR(15u) TFR(26u) TFR(6u)
  x0 += k1; x1 += k2 + 1u;
  TFR(17u) TFR(29u) TFR(16u) TFR(24u)
  x0 += k2; x1 += k0 + 2u;
  TFR(13u) TFR(15u) TFR(26u) TFR(6u)
  x0 += k0; x1 += k1 + 3u;
  TFR(17u) TFR(29u) TFR(16u) TFR(24u)
  x0 += k1; x1 += k2 + 4u;
  TFR(13u) TFR(15u) TFR(26u) TFR(6u)
  x0 += k2; x1 += k0 + 5u;
#undef TFR
  return make_uint2(x0, x1);
}

__device__ __forceinline__ bool drop_elem(uint32_t j) {
  const uint2 r = threefry2x32(0u, 42u, 0u, j);
  return ((r.x ^ r.y) >> 31) != 0u;
}

// ---------------- f16 pack/unpack ----------------
union PairU { f16x2 h; uint32_t u; };
__device__ __forceinline__ uint32_t pack_f16x2(float lo, float hi) {
  PairU p; p.h[0] = (_Float16)lo; p.h[1] = (_Float16)hi; return p.u;
}
__device__ __forceinline__ float f16_lo(f16x2 v) { return (float)v[0]; }
__device__ __forceinline__ float f16_hi(f16x2 v) { return (float)v[1]; }

__device__ __forceinline__ void pk_acc(uint32_t& acc, uint32_t v) {
  PairU a, b; a.u = acc; b.u = v; a.h += b.h; acc = a.u;
}

union FragU { uint4 q; f16x8 f; };

// ---------------- K1: adj-build | W2T-pack | gemm1 (block-range split) ----------------
// Adjacency row per node (192 B, line-aligned): cnt int at +0, u16 slots at +4.
// The atomic and the subsequent slot store hit the SAME cache line (for d<=30),
// eliminating cnt false-sharing (1 node/line vs 16) and halving scatter lines.
__global__ __launch_bounds__(256, 8) void k1_adj_w2t_gemm1(
    const float* __restrict__ x, const float* __restrict__ W1,
    const float* __restrict__ W2, uint32_t* __restrict__ W2T,
    const int* __restrict__ src, const int* __restrict__ dst,
    uint8_t* __restrict__ adjr, int E, int adjBlocks,
    uint32_t* __restrict__ z1h) {
  __shared__ uint32_t WT[64 * 64];  // 16 KB, fragment-major (gemm1 region only)

  if (blockIdx.x < adjBlocks) {
    const int base = blockIdx.x * 1024 + threadIdx.x;
    int d[4], s[4];
    bool ok[4];
#pragma unroll
    for (int j = 0; j < 4; ++j) {
      const int e = base + j * 256;
      ok[j] = (e < E);
      d[j] = ok[j] ? dst[e] : 0;
      s[j] = ok[j] ? src[e] : 0;
    }
    int slot[4];
#pragma unroll
    for (int j = 0; j < 4; ++j)
      slot[j] = ok[j] ? atomicAdd((int*)(adjr + (size_t)d[j] * kRowB), 1) : kCap;
#pragma unroll
    for (int j = 0; j < 4; ++j)
      if (ok[j] && slot[j] < kCap)
        *(uint16_t*)(adjr + (size_t)d[j] * kRowB + 4 + 2 * slot[j]) = (uint16_t)s[j];
    return;
  }

  if (blockIdx.x < adjBlocks + kW2TBlocks) {
    const int w = (blockIdx.x - adjBlocks) * 256 + threadIdx.x;  // < 4096
    const int n = w >> 6, i = w & 63;
    W2T[w] = pack_f16x2(W2[(size_t)(2 * i) * 64 + n], W2[(size_t)(2 * i + 1) * 64 + n]);
    return;
  }

  // ---- gemm1 region ----
  const int gb = blockIdx.x - adjBlocks - kW2TBlocks;  // 0..1563
  const int cg = gb & 1;                               // column group: cols cg*64..+63

  // Stage this cg's half of W1, fragment-major (conflict-free B-fragment reads).
  for (int v = threadIdx.x; v < 64 * 64; v += 256) {
    const int i  = v >> 6;        // k-pair index 0..63
    const int nl = v & 63;        // local column 0..63
    const int kb = i >> 4, r = i & 15;
    const int quad_s = r >> 2, c = r & 3;
    const int ct = nl >> 4, mrow_s = nl & 15;
    const int n = cg * 64 + nl;
    WT[((ct * 4 + kb) * 4 + quad_s) * 64 + mrow_s * 4 + c] =
        pack_f16x2(W1[(size_t)(2 * i) * 128 + n], W1[(size_t)(2 * i + 1) * 128 + n]);
  }
  __syncthreads();

  const int lane = threadIdx.x & 63;
  const int wid  = threadIdx.x >> 6;
  const int rb   = (gb >> 1) * 4 + wid;  // -> rb 0..3127
  if (rb >= 3125) return;                // tail wave (after barrier)
  const int n0   = rb * 16;
  const int quad = lane >> 4;
  const int mrow = lane & 15;

  const float* xp = x + (size_t)(n0 + mrow) * 128 + quad * 8;
  f32x4 acc[4] = {{0.f,0.f,0.f,0.f},{0.f,0.f,0.f,0.f},{0.f,0.f,0.f,0.f},{0.f,0.f,0.f,0.f}};

#pragma unroll
  for (int kb = 0; kb < 4; ++kb) {
    const float4 lo = *reinterpret_cast<const float4*>(xp + kb * 32);
    const float4 hi = *reinterpret_cast<const float4*>(xp + kb * 32 + 4);
    FragU a;
    a.q = make_uint4(pack_f16x2(lo.x, lo.y), pack_f16x2(lo.z, lo.w),
                     pack_f16x2(hi.x, hi.y), pack_f16x2(hi.z, hi.w));
#pragma unroll
    for (int ct = 0; ct < 4; ++ct) {
      FragU b;
      b.q = *reinterpret_cast<const uint4*>(&WT[((ct * 4 + kb) * 4 + quad) * 64 + mrow * 4]);
      acc[ct] = __builtin_amdgcn_mfma_f32_16x16x32_f16(a.f, b.f, acc[ct], 0, 0, 0);
    }
  }

#pragma unroll
  for (int ct = 0; ct < 4; ++ct) {
#pragma unroll
    for (int r = 0; r < 4; ++r) {
      const float v = acc[ct][r];
      const float vOdd = __shfl(v, lane | 1);
      if ((lane & 1) == 0) {
        const int row = n0 + quad * 4 + r;
        z1h[(size_t)row * 64 + cg * 32 + ct * 8 + (mrow >> 1)] = pack_f16x2(v, vOdd);
      }
    }
  }
}

// ---------------- K2: agg1 (grouped dwordx4 gather) + gemm2 fused ----------------
// 2 nodes/wave. Lane = (group g=lane>>4, chunk fl=lane&15): one dwordx4 load
// covers 4 neighbors' full 256B rows. Adjacency from the u16 row (half bytes).
__global__ __launch_bounds__(256, 8) void agg1_gemm2(
    const uint32_t* __restrict__ z1h, const uint8_t* __restrict__ adjr,
    const float* __restrict__ b1,
    const uint32_t* __restrict__ zpad, const uint32_t* __restrict__ W2T,
    uint32_t* __restrict__ z2h) {
  __shared__ uint32_t WT[64 * 68];  // 17.4 KB W2 packed
  __shared__ uint32_t HT[8 * 68];   // 2.2 KB h-tile (8 rows/block)

  // Stage W2T linearly (conflict-free); consumed only after the post-agg barrier.
  for (int v = threadIdx.x; v < 64 * 64; v += 256)
    WT[(v >> 6) * 68 + (v & 63)] = W2T[v];

  const int lane = threadIdx.x & 63;
  const int wid  = threadIdx.x >> 6;
  const int n0   = blockIdx.x * 8;       // 6250 blocks * 8 nodes
  const int nA = n0 + 2 * wid, nB = nA + 1;
  const int g  = lane >> 4;   // neighbor group 0..3
  const int fl = lane & 15;   // 16B chunk within 256B row

  const uint4* zq = reinterpret_cast<const uint4*>(zpad);

  const uint8_t* rowA = adjr + (size_t)nA * kRowB;
  const uint8_t* rowB = adjr + (size_t)nB * kRowB;
  const int vaA = *(const uint16_t*)(rowA + 4 + 2 * lane);
  const int vaB = *(const uint16_t*)(rowB + 4 + 2 * lane);
  int dA = __builtin_amdgcn_readfirstlane(*(const int*)rowA); if (dA > kCap) dA = kCap;
  int dB = __builtin_amdgcn_readfirstlane(*(const int*)rowB); if (dB > kCap) dB = kCap;
  const int dm = (dA > dB) ? dA : dB;

  uint32_t aA[4], aB[4];
  {  // self: group 0 loads the node's own row, other groups read zeroed pad
    const uint4* pa = (g == 0) ? reinterpret_cast<const uint4*>(z1h + (size_t)nA * 64) : zq;
    const uint4* pb = (g == 0) ? reinterpret_cast<const uint4*>(z1h + (size_t)nB * 64) : zq;
    const uint4 va = pa[fl];
    const uint4 vb = pb[fl];
    aA[0] = va.x; aA[1] = va.y; aA[2] = va.z; aA[3] = va.w;
    aB[0] = vb.x; aB[1] = vb.y; aB[2] = vb.z; aB[3] = vb.w;
  }

  for (int e = 0; e < dm; e += 16) {
    uint4 lA[4], lB[4];
#pragma unroll
    for (int j = 0; j < 4; ++j) {
      const int sl = e + j * 4 + g;                 // neighbor slot for this lane
      const int ia = __shfl(vaA, sl);               // one bpermute distributes 4 ids
      const uint4* pa = (sl < dA) ? reinterpret_cast<const uint4*>(z1h + (size_t)ia * 64) : zq;
      lA[j] = pa[fl];
    }
#pragma unroll
    for (int j = 0; j < 4; ++j) {
      const int sl = e + j * 4 + g;
      const int ib = __shfl(vaB, sl);
      const uint4* pb = (sl < dB) ? reinterpret_cast<const uint4*>(z1h + (size_t)ib * 64) : zq;
      lB[j] = pb[fl];
    }
#pragma unroll
    for (int j = 0; j < 4; ++j) {
      pk_acc(aA[0], lA[j].x); pk_acc(aA[1], lA[j].y);
      pk_acc(aA[2], lA[j].z); pk_acc(aA[3], lA[j].w);
      pk_acc(aB[0], lB[j].x); pk_acc(aB[1], lB[j].y);
      pk_acc(aB[2], lB[j].z); pk_acc(aB[3], lB[j].w);
    }
  }

  // cross-group reduce (lanes differing in bits 4/5 = other neighbor groups)
#pragma unroll
  for (int c = 0; c < 4; ++c) {
    uint32_t t;
    t = (uint32_t)__shfl_xor((int)aA[c], 16); pk_acc(aA[c], t);
    t = (uint32_t)__shfl_xor((int)aA[c], 32); pk_acc(aA[c], t);
    t = (uint32_t)__shfl_xor((int)aB[c], 16); pk_acc(aB[c], t);
    t = (uint32_t)__shfl_xor((int)aB[c], 32); pk_acc(aB[c], t);
  }

  // each lane owns row-dword d = 4*fl + g (all 64 dwords covered exactly once)
  const int d = 4 * fl + g;
  const uint32_t mA = (g & 2) ? ((g & 1) ? aA[3] : aA[2]) : ((g & 1) ? aA[1] : aA[0]);
  const uint32_t mB = (g & 2) ? ((g & 1) ? aB[3] : aB[2]) : ((g & 1) ? aB[1] : aB[0]);
  const float2 bb2 = *reinterpret_cast<const float2*>(b1 + 2 * d);
  {
    PairU s; s.u = mA;
    float hx = fmaxf(f16_lo(s.h) + bb2.x, 0.0f);
    float hy = fmaxf(f16_hi(s.h) + bb2.y, 0.0f);
    const uint32_t j0 = (uint32_t)nA * 128u + 2u * (uint32_t)d;
    hx = drop_elem(j0)      ? 0.0f : hx * 2.0f;
    hy = drop_elem(j0 + 1u) ? 0.0f : hy * 2.0f;
    HT[(2 * wid) * 68 + d] = pack_f16x2(hx, hy);   // 64 distinct dwords: <=2 lanes/bank
  }
  {
    PairU s; s.u = mB;
    float hx = fmaxf(f16_lo(s.h) + bb2.x, 0.0f);
    float hy = fmaxf(f16_hi(s.h) + bb2.y, 0.0f);
    const uint32_t j0 = (uint32_t)nB * 128u + 2u * (uint32_t)d;
    hx = drop_elem(j0)      ? 0.0f : hx * 2.0f;
    hy = drop_elem(j0 + 1u) ? 0.0f : hy * 2.0f;
    HT[(2 * wid + 1) * 68 + d] = pack_f16x2(hx, hy);
  }
  __syncthreads();

  // ---- gemm2 phase: wave wid computes output cols [wid*16, wid*16+16) for
  // the block's 8 rows. A-fragment rows 8-15 clamped to 0-7 (outputs unwritten).
  const int quad = lane >> 4;
  const int mrow = lane & 15;
  const int ct   = wid;
  f32x4 acc = {0.f, 0.f, 0.f, 0.f};
#pragma unroll
  for (int kb = 0; kb < 4; ++kb) {
    FragU a;
    a.q = *reinterpret_cast<const uint4*>(&HT[(mrow & 7) * 68 + kb * 16 + quad * 4]);
    FragU b;
    b.q = *reinterpret_cast<const uint4*>(&WT[(ct * 16 + mrow) * 68 + kb * 16 + quad * 4]);
    acc = __builtin_amdgcn_mfma_f32_16x16x32_f16(a.f, b.f, acc, 0, 0, 0);
  }
#pragma unroll
  for (int r = 0; r < 4; ++r) {
    const float v = acc[r];
    const float vOdd = __shfl(v, lane | 1);
    const int rloc = quad * 4 + r;                 // D row = quad*4+reg
    if ((lane & 1) == 0 && rloc < 8) {
      z2h[(size_t)(n0 + rloc) * 32 + ct * 8 + (mrow >> 1)] = pack_f16x2(v, vOdd);
    }
  }
}

// ---------------- agg_out: out = z2[n] + sum z2[adj] + b2 (grouped gather) ----
// 128B rows: 8 groups x 8 lanes x 16B. One dwordx4 load = 8 neighbors' rows.
__global__ __launch_bounds__(256, 8) void agg_out(
    const uint32_t* __restrict__ z2h, const uint8_t* __restrict__ adjr,
    const float* __restrict__ b2,
    const uint32_t* __restrict__ zpad, float* __restrict__ out) {
  const int lane = threadIdx.x & 63;
  const int wid  = threadIdx.x >> 6;
  const int pp = blockIdx.x * 4 + wid;   // 6250 blocks
  const int nA = pp * 2, nB = pp * 2 + 1;
  const int g8 = lane >> 3;   // neighbor group 0..7
  const int f8 = lane & 7;    // 16B chunk within 128B row

  const uint4* zq = reinterpret_cast<const uint4*>(zpad);

  const uint8_t* rowA = adjr + (size_t)nA * kRowB;
  const uint8_t* rowB = adjr + (size_t)nB * kRowB;
  const int vaA = *(const uint16_t*)(rowA + 4 + 2 * lane);
  const int vaB = *(const uint16_t*)(rowB + 4 + 2 * lane);
  int dA = __builtin_amdgcn_readfirstlane(*(const int*)rowA); if (dA > kCap) dA = kCap;
  int dB = __builtin_amdgcn_readfirstlane(*(const int*)rowB); if (dB > kCap) dB = kCap;
  const int dm = (dA > dB) ? dA : dB;

  uint32_t aA[4], aB[4];
  {
    const uint4* pa = (g8 == 0) ? reinterpret_cast<const uint4*>(z2h + (size_t)nA * 32) : zq;
    const uint4* pb = (g8 == 0) ? reinterpret_cast<const uint4*>(z2h + (size_t)nB * 32) : zq;
    const uint4 va = pa[f8];
    const uint4 vb = pb[f8];
    aA[0] = va.x; aA[1] = va.y; aA[2] = va.z; aA[3] = va.w;
    aB[0] = vb.x; aB[1] = vb.y; aB[2] = vb.z; aB[3] = vb.w;
  }

  for (int e = 0; e < dm; e += 16) {
    uint4 lA[2], lB[2];
#pragma unroll
    for (int j = 0; j < 2; ++j) {
      const int sl = e + j * 8 + g8;
      const int ia = __shfl(vaA, sl);
      const uint4* pa = (sl < dA) ? reinterpret_cast<const uint4*>(z2h + (size_t)ia * 32) : zq;
      lA[j] = pa[f8];
    }
#pragma unroll
    for (int j = 0; j < 2; ++j) {
      const int sl = e + j * 8 + g8;
      const int ib = __shfl(vaB, sl);
      const uint4* pb = (sl < dB) ? reinterpret_cast<const uint4*>(z2h + (size_t)ib * 32) : zq;
      lB[j] = pb[f8];
    }
#pragma unroll
    for (int j = 0; j < 2; ++j) {
      pk_acc(aA[0], lA[j].x); pk_acc(aA[1], lA[j].y);
      pk_acc(aA[2], lA[j].z); pk_acc(aA[3], lA[j].w);
      pk_acc(aB[0], lB[j].x); pk_acc(aB[1], lB[j].y);
      pk_acc(aB[2], lB[j].z); pk_acc(aB[3], lB[j].w);
    }
  }

  // cross-group reduce over 8 groups (lane bits 3,4,5)
#pragma unroll
  for (int c = 0; c < 4; ++c) {
    uint32_t t;
    t = (uint32_t)__shfl_xor((int)aA[c], 8);  pk_acc(aA[c], t);
    t = (uint32_t)__shfl_xor((int)aA[c], 16); pk_acc(aA[c], t);
    t = (uint32_t)__shfl_xor((int)aA[c], 32); pk_acc(aA[c], t);
    t = (uint32_t)__shfl_xor((int)aB[c], 8);  pk_acc(aB[c], t);
    t = (uint32_t)__shfl_xor((int)aB[c], 16); pk_acc(aB[c], t);
    t = (uint32_t)__shfl_xor((int)aB[c], 32); pk_acc(aB[c], t);
  }

  // lane owns row-dword d = 4*f8 + (g8&3); groups 4..7 are redundant copies
  const int d = 4 * f8 + (g8 & 3);
  const uint32_t mA = (g8 & 2) ? ((g8 & 1) ? aA[3] : aA[2]) : ((g8 & 1) ? aA[1] : aA[0]);
  const uint32_t mB = (g8 & 2) ? ((g8 & 1) ? aB[3] : aB[2]) : ((g8 & 1) ? aB[1] : aB[0]);
  if (g8 < 4) {
    const float2 bb2 = *reinterpret_cast<const float2*>(b2 + 2 * d);
    PairU sA; sA.u = mA;
    float2 oA; oA.x = f16_lo(sA.h) + bb2.x; oA.y = f16_hi(sA.h) + bb2.y;
    *reinterpret_cast<float2*>(out + (size_t)nA * 64 + 2 * d) = oA;
    PairU sB; sB.u = mB;
    float2 oB; oB.x = f16_lo(sB.h) + bb2.x; oB.y = f16_hi(sB.h) + bb2.y;
    *reinterpret_cast<float2*>(out + (size_t)nB * 64 + 2 * d) = oB;
  }
}

// ---------------- launch ----------------
extern "C" void kernel_launch(void* const* d_in, const int* in_sizes, int n_in,
                              void* d_out, int out_size, void* d_ws, size_t ws_size,
                              hipStream_t stream) {
  const float* x  = (const float*)d_in[0];
  const int*   ei = (const int*)d_in[1];
  const float* W1 = (const float*)d_in[2];
  const float* b1 = (const float*)d_in[3];
  const float* W2 = (const float*)d_in[4];
  const float* b2 = (const float*)d_in[5];
  float* out = (float*)d_out;

  const int E = in_sizes[1] / 2;  // edge_index is (2, E), int32 on device
  const int* src = ei;
  const int* dst = ei + E;

  // d_ws layout:
  uint32_t* zpad = (uint32_t*)d_ws;                        // 64 dwords = 256 B, zeroed
  uint8_t*  adjr = (uint8_t*)d_ws + 256;                   // 50000 x 192 B = 9.6 MB
  uint32_t* z1h  = (uint32_t*)(adjr + (size_t)kN * kRowB); // 50000*64 dwords = 12.8 MB
  uint32_t* z2h  = z1h + (size_t)kN * 64;                  // 50000*32 dwords = 6.4 MB
  uint32_t* W2T  = z2h + (size_t)kN * 32;                  // 4096 dwords = 16 KB

  const int adjBlocks = (E + 1023) / 1024;  // 4 edges/thread

  hipMemsetAsync(d_ws, 0, 256 + (size_t)kN * kRowB, stream);  // zpad + adjr (cnt=0)
  k1_adj_w2t_gemm1<<<adjBlocks + kW2TBlocks + kGemm1Blocks, 256, 0, stream>>>(
      x, W1, W2, W2T, src, dst, adjr, E, adjBlocks, z1h);
  agg1_gemm2<<<6250, 256, 0, stream>>>(
      z1h, adjr, b1, zpad, W2T, z2h);
  agg_out<<<6250, 256, 0, stream>>>(
      z2h, adjr, b2, zpad, out);
}